// Round 4
// baseline (108.177 us; speedup 1.0000x reference)
//
#include <hip/hip_runtime.h>
#include <hip/hip_bf16.h>

// B=8, N=64, P=128, DNODE=2048, DEDGE=1024, DEMB=512, E=32768
// edge_locating_tensor is the canonical meshgrid -> lookup(b,i,j)=b*4096+i*64+j.
// Only 2*B*P=2048 of 32768 edge rows used; (e1+e2)*0.5 folds into the GEMM input.
// SINGLE persistent kernel (256 blocks, co-resident) with 2 grid barriers:
//   phase1 prep (W-transpose, x-cvt, b3, gather) | phase2 both GEMMs | phase3 scores+first-half.

typedef _Float16 h16;
typedef h16 h16x4 __attribute__((ext_vector_type(4)));
typedef h16 h16x8 __attribute__((ext_vector_type(8)));
typedef float f32x4 __attribute__((ext_vector_type(4)));

// ---------------- ws layout (bytes) ----------------
static const long O_XH   = 0;         // 512*2048*2  = 2097152   x as f16
static const long O_W3T  = 2097152;   // 1536*2048*2 = 6291456   phi|psi|node K-major
static const long O_WREL = 8388608;   // 512*1024*2  = 1048576   Wrel K-major
static const long O_G    = 9437184;   // 1024*1024*2 = 2097152   0.5*(f_fwd+f_rev) f16
static const long O_B3   = 11534336;  // 1536*4
static const long O_Y    = 11540480;  // 512*1536*4  = 3145728   phi|psi|node fp32
static const long O_YH   = 14686208;  // 512*1024*2  = 1048576   phi|psi f16
static const long O_CNT  = 15734784;  // 4   barrier counter (memset to 0 per call)

__device__ __forceinline__ void grid_barrier(unsigned* cnt, unsigned target) {
  __syncthreads();
  if (threadIdx.x == 0) {
    __threadfence();  // device-scope release: write back dirty L2 (cross-XCD)
    __hip_atomic_fetch_add(cnt, 1u, __ATOMIC_ACQ_REL, __HIP_MEMORY_SCOPE_AGENT);
    while (__hip_atomic_load(cnt, __ATOMIC_ACQUIRE, __HIP_MEMORY_SCOPE_AGENT) < target)
      __builtin_amdgcn_s_sleep(2);
  }
  __syncthreads();
}

__device__ __forceinline__ void mfma_compute(
    const h16 (*__restrict__ As)[72], const h16 (*__restrict__ Bs)[72],
    int wm, int wn, int fr, int kg, f32x4 acc[2][2]) {
#pragma unroll
  for (int kc = 0; kc < 2; ++kc) {
    int kb = kc*32 + kg;
    h16x8 fa0 = *(const h16x8*)&As[wm*32 + fr][kb];
    h16x8 fa1 = *(const h16x8*)&As[wm*32 + 16 + fr][kb];
    h16x8 fb0 = *(const h16x8*)&Bs[wn*32 + fr][kb];
    h16x8 fb1 = *(const h16x8*)&Bs[wn*32 + 16 + fr][kb];
    acc[0][0] = __builtin_amdgcn_mfma_f32_16x16x32_f16(fa0, fb0, acc[0][0], 0,0,0);
    acc[0][1] = __builtin_amdgcn_mfma_f32_16x16x32_f16(fa0, fb1, acc[0][1], 0,0,0);
    acc[1][0] = __builtin_amdgcn_mfma_f32_16x16x32_f16(fa1, fb0, acc[1][0], 0,0,0);
    acc[1][1] = __builtin_amdgcn_mfma_f32_16x16x32_f16(fa1, fb1, acc[1][1], 0,0,0);
  }
}

// Double-buffered reg-staged pipeline, ONE barrier per K-step.
#define GEMM_PIPELINE(Agp, Bgp, K)                                        \
  {                                                                       \
    h16x8 ra0 = *(const h16x8*)(Agp);                                     \
    h16x8 ra1 = *(const h16x8*)(Agp + 8);                                 \
    h16x8 rb0 = *(const h16x8*)(Bgp);                                     \
    h16x8 rb1 = *(const h16x8*)(Bgp + 8);                                 \
    *(h16x8*)&As[0][srow][skp]   = ra0;                                   \
    *(h16x8*)&As[0][srow][skp+8] = ra1;                                   \
    *(h16x8*)&Bs[0][srow][skp]   = rb0;                                   \
    *(h16x8*)&Bs[0][srow][skp+8] = rb1;                                   \
    __syncthreads();                                                      \
    int cur = 0;                                                          \
    for (int k0 = 64; k0 < (K); k0 += 64) {                               \
      ra0 = *(const h16x8*)(Agp + k0);                                    \
      ra1 = *(const h16x8*)(Agp + k0 + 8);                                \
      rb0 = *(const h16x8*)(Bgp + k0);                                    \
      rb1 = *(const h16x8*)(Bgp + k0 + 8);                                \
      mfma_compute(As[cur], Bs[cur], wm, wn, fr, kg, acc);                \
      int nxt = cur ^ 1;                                                  \
      *(h16x8*)&As[nxt][srow][skp]   = ra0;                               \
      *(h16x8*)&As[nxt][srow][skp+8] = ra1;                               \
      *(h16x8*)&Bs[nxt][srow][skp]   = rb0;                               \
      *(h16x8*)&Bs[nxt][srow][skp+8] = rb1;                               \
      __syncthreads();                                                    \
      cur = nxt;                                                          \
    }                                                                     \
    mfma_compute(As[cur], Bs[cur], wm, wn, fr, kg, acc);                  \
  }

__global__ __launch_bounds__(256, 1) void k_fused(
    const float* __restrict__ x, const float* __restrict__ feat,
    const float* __restrict__ Wphi, const float* __restrict__ bphi,
    const float* __restrict__ Wpsi, const float* __restrict__ bpsi,
    const float* __restrict__ Wnode, const float* __restrict__ bnode,
    const float* __restrict__ Wrel, const float* __restrict__ brel,
    const int* __restrict__ pairs, float* __restrict__ out,
    h16* __restrict__ xh, h16* __restrict__ W3t, h16* __restrict__ Wrelt,
    h16* __restrict__ G, float* __restrict__ b3, float* __restrict__ Y,
    h16* __restrict__ Yh, unsigned* cnt) {
  __shared__ float t[32][33];
  __shared__ __align__(16) h16 As[2][64][72];
  __shared__ __align__(16) h16 Bs[2][64][72];
  int bid = blockIdx.x, tid = threadIdx.x;

  // ================= phase 1: prep =================
  // 3584 weight-transpose 32x32 units, 14 per block
#pragma unroll 1
  for (int u0 = 0; u0 < 14; ++u0) {
    int u = bid * 14 + u0;
    const float* src; h16* dst; int K, tk, tn;
    if (u < 3072) {
      int mat = u >> 10, rem = u & 1023;
      tk = rem >> 4; tn = rem & 15;
      src = mat == 0 ? Wphi : (mat == 1 ? Wpsi : Wnode);
      K = 2048; dst = W3t + (long)mat * 512 * 2048;
    } else {
      int rem = u - 3072;
      tk = rem >> 4; tn = rem & 15;
      src = Wrel; K = 1024; dst = Wrelt;
    }
    int tx = tid & 31, ty = tid >> 5;
#pragma unroll
    for (int it = 0; it < 4; ++it)
      t[ty + it*8][tx] = src[(long)(tk*32 + ty + it*8)*512 + tn*32 + tx];
    __syncthreads();
#pragma unroll
    for (int it = 0; it < 4; ++it)
      dst[(long)(tn*32 + ty + it*8)*K + tk*32 + tx] = (h16)t[tx][ty + it*8];
    __syncthreads();
  }
  // x -> f16 (512 units, 2 per block)
#pragma unroll 1
  for (int u0 = 0; u0 < 2; ++u0) {
    int idx = ((bid*2 + u0)*256 + tid) * 8;
    const float4* xv = (const float4*)(x + idx);
    float4 v0 = xv[0], v1 = xv[1];
    h16x8 o;
    o[0]=(h16)v0.x; o[1]=(h16)v0.y; o[2]=(h16)v0.z; o[3]=(h16)v0.w;
    o[4]=(h16)v1.x; o[5]=(h16)v1.y; o[6]=(h16)v1.z; o[7]=(h16)v1.w;
    *(h16x8*)(xh + idx) = o;
  }
  // b3 concat bias
  if (bid < 6) {
    int i = bid*256 + tid;
    b3[i] = i < 512 ? bphi[i] : (i < 1024 ? bpsi[i-512] : bnode[i-1024]);
  }
  // gather+average edge features (1024 units, 4 per block)
#pragma unroll 1
  for (int u0 = 0; u0 < 4; ++u0) {
    int r = bid*4 + u0;          // r = b*128 + p
    int b = r >> 7;
    int i0 = pairs[r*2], i1 = pairs[r*2+1];
    const float4* f0 = (const float4*)(feat + (long)((b*64 + i0)*64 + i1) * 1024);
    const float4* f1 = (const float4*)(feat + (long)((b*64 + i1)*64 + i0) * 1024);
    float4 a = f0[tid], c = f1[tid];
    h16x4 o;
    o[0]=(h16)(0.5f*(a.x+c.x)); o[1]=(h16)(0.5f*(a.y+c.y));
    o[2]=(h16)(0.5f*(a.z+c.z)); o[3]=(h16)(0.5f*(a.w+c.w));
    *(h16x4*)(G + (long)r*1024 + tid*4) = o;
  }

  grid_barrier(cnt, 256);

  // ================= phase 2: both GEMMs =================
  int lane = tid & 63, wave = tid >> 6;
  int wm = wave >> 1, wn = wave & 1;
  int srow = tid >> 2, skp = (tid & 3) * 16;
  int fr = lane & 15, kg = (lane >> 4) * 8;
  int ntile = bid < 192 ? 1 : 2;
#pragma unroll 1
  for (int ti = 0; ti < ntile; ++ti) {
    if (ti) __syncthreads();
    const h16 *A, *Bt; const float* bias; float* C;
    int K, ldc, tileM, tileN;
    if (bid < 192) {             // Y(512x1536) = xh @ W3t^T + b3
      A = xh; Bt = W3t; bias = b3; C = Y; K = 2048; ldc = 1536;
      tileM = (bid / 24) * 64; tileN = (bid % 24) * 64;
    } else {                     // edge(1024x512) = G @ Wrelt^T + brel
      int e = (bid - 192) * 2 + ti;
      A = G; Bt = Wrelt; bias = brel; C = out + 32768 + 512; K = 1024; ldc = 1024;
      tileM = (e >> 3) * 64; tileN = (e & 7) * 64;
    }
    const h16* Agp = A + (long)(tileM + srow) * K + skp;
    const h16* Bgp = Bt + (long)(tileN + srow) * K + skp;
    f32x4 acc[2][2] = {};
    GEMM_PIPELINE(Agp, Bgp, K);
    int r0 = 4 * (lane >> 4), c0 = lane & 15;
    bool wantYh = (bid < 192) && (tileN < 1024);
#pragma unroll
    for (int m = 0; m < 2; ++m)
#pragma unroll
      for (int n = 0; n < 2; ++n) {
        int row = tileM + wm*32 + m*16 + r0;
        int col = tileN + wn*32 + n*16 + c0;
        float bb = bias[col];
#pragma unroll
        for (int r = 0; r < 4; ++r) {
          float v = acc[m][n][r] + bb;
          C[(long)(row + r) * ldc + col] = v;
          if (wantYh) Yh[(long)(row + r) * 1024 + col] = (h16)v;
        }
      }
  }

  grid_barrier(cnt, 512);

  // ================= phase 3: scores + first half =================
  if (bid < 8) {
    // S_b = phi_h @ psi_h^T (64x64, K=512), fused sigmoid
    const h16* Ab = Yh + (long)bid * 64 * 1024;
    const h16* Agp = Ab + (long)srow * 1024 + skp;
    const h16* Bgp = Ab + (long)srow * 1024 + 512 + skp;
    f32x4 acc[2][2] = {};
    GEMM_PIPELINE(Agp, Bgp, 512);
    int r0 = 4 * (lane >> 4), c0 = lane & 15;
    float* ob = out + (long)bid * 4096;
#pragma unroll
    for (int m = 0; m < 2; ++m)
#pragma unroll
      for (int n = 0; n < 2; ++n) {
        int row = wm*32 + m*16 + r0;
        int col = wn*32 + n*16 + c0;
#pragma unroll
        for (int r = 0; r < 4; ++r) {
          float s = acc[m][n][r];
          ob[(long)(row + r) * 64 + col] = 1.f / (1.f + expf(-s));
        }
      }
  } else {
    // first half: 0.5*(node_emb[b,i0]+node_emb[b,i1]); units 0..1023 over blocks 8..255
#pragma unroll 1
    for (int u = bid - 8; u < 1024; u += 248) {
      int b = u >> 7;
      int i0 = pairs[u*2], i1 = pairs[u*2+1];
      const float* n0 = Y + (long)(b*64 + i0)*1536 + 1024;
      const float* n1 = Y + (long)(b*64 + i1)*1536 + 1024;
      float* o = out + 32768 + (long)u*1024;
      for (int c = tid; c < 512; c += 256)
        o[c] = 0.5f*(n0[c] + n1[c]);
    }
  }
}

extern "C" void kernel_launch(void* const* d_in, const int* in_sizes, int n_in,
                              void* d_out, int out_size, void* d_ws, size_t ws_size,
                              hipStream_t stream) {
  const float* x     = (const float*)d_in[0];
  const float* feat  = (const float*)d_in[1];
  const float* Wphi  = (const float*)d_in[2];
  const float* bphi  = (const float*)d_in[3];
  const float* Wpsi  = (const float*)d_in[4];
  const float* bpsi  = (const float*)d_in[5];
  const float* Wnode = (const float*)d_in[6];
  const float* bnode = (const float*)d_in[7];
  const float* Wrel  = (const float*)d_in[8];
  const float* brel  = (const float*)d_in[9];
  const int*   pairs = (const int*)d_in[10];
  float* out = (float*)d_out;
  char* ws = (char*)d_ws;

  hipMemsetAsync(ws + O_CNT, 0, 4, stream);
  k_fused<<<dim3(256), dim3(256), 0, stream>>>(
      x, feat, Wphi, bphi, Wpsi, bpsi, Wnode, bnode, Wrel, brel, pairs, out,
      (h16*)(ws + O_XH), (h16*)(ws + O_W3T), (h16*)(ws + O_WREL),
      (h16*)(ws + O_G), (float*)(ws + O_B3), (float*)(ws + O_Y),
      (h16*)(ws + O_YH), (unsigned*)(ws + O_CNT));
}